// Round 9
// baseline (1419.446 us; speedup 1.0000x reference)
//
#include <hip/hip_runtime.h>
#include <math.h>

#define GN 256
#define VOLN (GN * GN * GN)
#define VOLBYTES ((size_t)VOLN * sizeof(float))
#define RAD 16          // truncation radius of the exact circular-conv kernel

// spatial cells for point sorting: 16^3 voxels per cell, 16^3 = 4096 cells
#define CELLW 16
#define CPA   16        // cells per axis
#define CELLS (CPA * CPA * CPA)
#define TILEW (CELLW + 1)                 // 17
#define TILEN (TILEW * TILEW * TILEW)     // 4913

#define HB  1024        // threads per hist/scatter block
#define PPT 16          // points per thread

__device__ __forceinline__ int cell_of(float g0, float g1, float g2) {
    int b0 = (int)floorf(g0), b1 = (int)floorf(g1), b2 = (int)floorf(g2);
    b0 = min(max(b0, 0), 255); b1 = min(max(b1, 0), 255); b2 = min(max(b2, 0), 255);
    return ((b0 >> 4) << 8) | ((b1 >> 4) << 4) | (b2 >> 4);
}

// ---------------------------------------------------------------------------
// Pass 1: per-block LDS histogram -> ~70k global atomics instead of 500k
// ---------------------------------------------------------------------------
__global__ __launch_bounds__(HB) void hist_kernel(const float* __restrict__ means,
                                                  unsigned* __restrict__ cellcnt, int n) {
    __shared__ unsigned lh[CELLS];
    int t = threadIdx.x;
    for (int i = t; i < CELLS; i += HB) lh[i] = 0u;
    __syncthreads();
    int base = blockIdx.x * (HB * PPT);
    for (int j = 0; j < PPT; ++j) {
        int p = base + j * HB + t;
        if (p < n) {
            float g0 = fmaf(means[3 * p + 0], 128.f, 128.f);
            float g1 = fmaf(means[3 * p + 1], 128.f, 128.f);
            float g2 = fmaf(means[3 * p + 2], 128.f, 128.f);
            atomicAdd(&lh[cell_of(g0, g1, g2)], 1u);
        }
    }
    __syncthreads();
    for (int i = t; i < CELLS; i += HB) {
        unsigned v = lh[i];
        if (v) atomicAdd(&cellcnt[i], v);
    }
}

// ---------------------------------------------------------------------------
// Pass 2: exclusive scan of 4096 cell counts (single block); writes cellstart
// (preserved for cellsplat) and cursor (mutated by scatter).
// ---------------------------------------------------------------------------
__global__ __launch_bounds__(1024) void scan_kernel(const unsigned* __restrict__ cellcnt,
                                                    unsigned* __restrict__ cellstart,
                                                    unsigned* __restrict__ cursor) {
    __shared__ unsigned sums[1024];
    int t = threadIdx.x;
    unsigned c[4], loc[4], tot = 0u;
#pragma unroll
    for (int i = 0; i < 4; ++i) { c[i] = cellcnt[t * 4 + i]; loc[i] = tot; tot += c[i]; }
    sums[t] = tot;
    __syncthreads();
    for (int ofs = 1; ofs < 1024; ofs <<= 1) {
        unsigned v = (t >= ofs) ? sums[t - ofs] : 0u;
        __syncthreads();
        sums[t] += v;
        __syncthreads();
    }
    unsigned base = (t == 0) ? 0u : sums[t - 1];
#pragma unroll
    for (int i = 0; i < 4; ++i) {
        unsigned s = base + loc[i];
        cellstart[t * 4 + i] = s;
        cursor[t * 4 + i] = s;
    }
}

// ---------------------------------------------------------------------------
// Pass 3: 3-phase scatter. LDS count -> one global reserve per (block,cell)
// -> LDS-ranked placement. Stores transformed coords + relu(weight).
// ---------------------------------------------------------------------------
__global__ __launch_bounds__(HB) void scatter_kernel(const float* __restrict__ means,
                                                     const float* __restrict__ weights,
                                                     unsigned* __restrict__ cursor,
                                                     float4* __restrict__ sorted, int n) {
    __shared__ unsigned lh[CELLS];
    int t = threadIdx.x;
    for (int i = t; i < CELLS; i += HB) lh[i] = 0u;
    __syncthreads();
    int base = blockIdx.x * (HB * PPT);
    for (int j = 0; j < PPT; ++j) {
        int p = base + j * HB + t;
        if (p < n) {
            float g0 = fmaf(means[3 * p + 0], 128.f, 128.f);
            float g1 = fmaf(means[3 * p + 1], 128.f, 128.f);
            float g2 = fmaf(means[3 * p + 2], 128.f, 128.f);
            atomicAdd(&lh[cell_of(g0, g1, g2)], 1u);
        }
    }
    __syncthreads();
    for (int i = t; i < CELLS; i += HB) {
        unsigned v = lh[i];
        lh[i] = v ? atomicAdd(&cursor[i], v) : 0u;   // lh now holds block's base
    }
    __syncthreads();
    for (int j = 0; j < PPT; ++j) {
        int p = base + j * HB + t;
        if (p < n) {
            float g0 = fmaf(means[3 * p + 0], 128.f, 128.f);
            float g1 = fmaf(means[3 * p + 1], 128.f, 128.f);
            float g2 = fmaf(means[3 * p + 2], 128.f, 128.f);
            unsigned pos = atomicAdd(&lh[cell_of(g0, g1, g2)], 1u);
            sorted[pos] = make_float4(g0, g1, g2, fmaxf(weights[p], 0.f));
        }
    }
}

// ---------------------------------------------------------------------------
// Pass 4: per-cell splat into a 17^3 LDS tile. Interior voxels [1..15]^3 are
// exclusively owned -> plain store onto the zeroed volume; halo faces use
// atomics. OOB corners dropped (JAX scatter semantics).
// ---------------------------------------------------------------------------
__global__ __launch_bounds__(256) void cellsplat_kernel(const float4* __restrict__ sorted,
                                                        const unsigned* __restrict__ cellstart,
                                                        float* __restrict__ vol, int n) {
    __shared__ float tile[TILEN];
    int c = blockIdx.x;
    unsigned start = cellstart[c];
    unsigned end = (c == CELLS - 1) ? (unsigned)n : cellstart[c + 1];
    if (start == end) return;                 // block-uniform
    for (int i = threadIdx.x; i < TILEN; i += 256) tile[i] = 0.f;
    __syncthreads();
    int cb0 = (c >> 8) << 4, cb1 = ((c >> 4) & 15) << 4, cb2 = (c & 15) << 4;
    for (unsigned p0 = start; p0 < end; p0 += 256) {
        unsigned p = p0 + threadIdx.x;
        if (p < end) {
            float4 q = sorted[p];
            float f0 = floorf(q.x), f1 = floorf(q.y), f2 = floorf(q.z);
            int b0 = (int)f0, b1 = (int)f1, b2 = (int)f2;
            float r0 = q.x - f0, r1 = q.y - f1, r2 = q.z - f2;
            float c0v[2] = {1.f - r0, r0}, c1v[2] = {1.f - r1, r1}, c2v[2] = {1.f - r2, r2};
#pragma unroll
            for (int o0 = 0; o0 < 2; ++o0) {
                int v0 = b0 + o0, t0 = v0 - cb0;
                if ((unsigned)t0 > 16u || (unsigned)v0 > 255u) continue;
#pragma unroll
                for (int o1 = 0; o1 < 2; ++o1) {
                    int v1 = b1 + o1, t1 = v1 - cb1;
                    if ((unsigned)t1 > 16u || (unsigned)v1 > 255u) continue;
                    float w01 = c0v[o0] * c1v[o1] * q.w;
#pragma unroll
                    for (int o2 = 0; o2 < 2; ++o2) {
                        int v2 = b2 + o2, t2 = v2 - cb2;
                        if ((unsigned)t2 > 16u || (unsigned)v2 > 255u) continue;
                        atomicAdd(&tile[t0 * (TILEW * TILEW) + t1 * TILEW + t2], w01 * c2v[o2]);
                    }
                }
            }
        }
    }
    __syncthreads();
    for (int i = threadIdx.x; i < TILEN; i += 256) {
        float val = tile[i];
        if (val == 0.f) continue;
        int t0 = i / (TILEW * TILEW);
        int rem = i - t0 * (TILEW * TILEW);
        int t1 = rem / TILEW, t2 = rem - t1 * TILEW;
        int v0 = cb0 + t0, v1 = cb1 + t1, v2 = cb2 + t2;
        bool interior = (t0 >= 1 && t0 <= 15) && (t1 >= 1 && t1 <= 15) && (t2 >= 1 && t2 <= 15);
        if (interior) {
            vol[(v0 << 16) | (v1 << 8) | v2] = val;            // exclusive ownership
        } else if (v0 < 256 && v1 < 256 && v2 < 256) {
            atomicAdd(&vol[(v0 << 16) | (v1 << 8) | v2], val); // shared halo
        }
    }
}

// ---------------------------------------------------------------------------
// Exact 1-D blur taps (parallel DFT sum): h[m] = (1/256) * sum_k
//   exp(-2 pi^2 sigma^2 f_k^2) * cos(2 pi k m / 256)
// Integer angle reduction (k*m mod 256) keeps fp32 cos exact-range.
// ---------------------------------------------------------------------------
__global__ __launch_bounds__(256) void taps_kernel(const float* __restrict__ sigma_param,
                                                   float* __restrict__ h) {
    __shared__ float red[4];
    int k = threadIdx.x;
    float s = fmaxf(sigma_param[0], 0.f);
    int kk = (k < 128) ? k : k - 256;
    float f = (float)kk / 256.f;
    float cc = 2.f * (float)(M_PI * M_PI) * s * s;
    float term = expf(-cc * f * f);
    int wid = k >> 6, lane = k & 63;
    for (int m = 0; m <= RAD; ++m) {
        int idx = (k * m) & 255;
        float v = term * cosf((float)idx * (2.f * (float)M_PI / 256.f));
#pragma unroll
        for (int o = 32; o > 0; o >>= 1) v += __shfl_down(v, o, 64);
        if (lane == 0) red[wid] = v;
        __syncthreads();
        if (k == 0) h[m] = (red[0] + red[1] + red[2] + red[3]) * (1.f / 256.f);
        __syncthreads();
    }
}

// ---------------------------------------------------------------------------
// Separable circular convolutions, LDS-tiled + register-windowed.
// Volume index: (i0<<16)|(i1<<8)|i2, i2 contiguous.
// ---------------------------------------------------------------------------

// conv along i0: tile 96 rows (64 out + 2*16 halo) x 128 cols; each thread
// computes 32 consecutive i0 outputs from a 64-row register window.
__global__ __launch_bounds__(256) void conv_d0_kernel(const float* __restrict__ in,
                                                      float* __restrict__ out,
                                                      const float* __restrict__ h) {
    __shared__ float tile[96][128];
    float shv[17];
#pragma unroll
    for (int j = 0; j < 17; ++j) shv[j] = h[j];
    int i1 = blockIdx.x, t0 = blockIdx.y, ch = blockIdx.z;
    int colbase = ch << 7;
#pragma unroll
    for (int it = 0; it < 48; ++it) {
        int e = it * 256 + threadIdx.x;
        int r = e >> 7, cc = e & 127;
        int i0 = ((t0 << 6) + r - 16) & 255;
        tile[r][cc] = in[(i0 << 16) | (i1 << 8) | (colbase + cc)];
    }
    __syncthreads();
    int c = threadIdx.x & 127;
    int ob = (threadIdx.x >> 7) << 5;        // 0 or 32
    float acc[32];
#pragma unroll
    for (int j = 0; j < 32; ++j) acc[j] = 0.f;
#pragma unroll
    for (int rr = 0; rr < 64; ++rr) {
        float v = tile[ob + rr][c];
#pragma unroll
        for (int jj = 0; jj < 32; ++jj) {
            int d = rr - jj - 16;
            if (d >= -16 && d <= 16) acc[jj] = fmaf(shv[d < 0 ? -d : d], v, acc[jj]);
        }
    }
    int o0base = (t0 << 6) + ob;
#pragma unroll
    for (int jj = 0; jj < 32; ++jj)
        out[((o0base + jj) << 16) | (i1 << 8) | (colbase + c)] = acc[jj];
}

// conv along i1: identical structure, roles of i0/i1 swapped.
__global__ __launch_bounds__(256) void conv_d1_kernel(const float* __restrict__ in,
                                                      float* __restrict__ out,
                                                      const float* __restrict__ h) {
    __shared__ float tile[96][128];
    float shv[17];
#pragma unroll
    for (int j = 0; j < 17; ++j) shv[j] = h[j];
    int i0 = blockIdx.x, t1 = blockIdx.y, ch = blockIdx.z;
    int colbase = ch << 7;
#pragma unroll
    for (int it = 0; it < 48; ++it) {
        int e = it * 256 + threadIdx.x;
        int r = e >> 7, cc = e & 127;
        int i1 = ((t1 << 6) + r - 16) & 255;
        tile[r][cc] = in[(i0 << 16) | (i1 << 8) | (colbase + cc)];
    }
    __syncthreads();
    int c = threadIdx.x & 127;
    int ob = (threadIdx.x >> 7) << 5;
    float acc[32];
#pragma unroll
    for (int j = 0; j < 32; ++j) acc[j] = 0.f;
#pragma unroll
    for (int rr = 0; rr < 64; ++rr) {
        float v = tile[ob + rr][c];
#pragma unroll
        for (int jj = 0; jj < 32; ++jj) {
            int d = rr - jj - 16;
            if (d >= -16 && d <= 16) acc[jj] = fmaf(shv[d < 0 ? -d : d], v, acc[jj]);
        }
    }
    int o1base = (t1 << 6) + ob;
#pragma unroll
    for (int jj = 0; jj < 32; ++jj)
        out[(i0 << 16) | ((o1base + jj) << 8) | (colbase + c)] = acc[jj];
}

// conv along i2 (contiguous): 4 rows/block; thread computes 4 consecutive i2
// from a 36-float register window loaded as 9x float4 (conflict-free b128).
__global__ __launch_bounds__(256) void conv_d2_kernel(const float* __restrict__ in,
                                                      float* __restrict__ out,
                                                      const float* __restrict__ h) {
    __shared__ float tile[4][256];
    float shv[17];
#pragma unroll
    for (int j = 0; j < 17; ++j) shv[j] = h[j];
    int bx = blockIdx.x;                       // 16384 blocks
    size_t base = (size_t)bx * 1024;
#pragma unroll
    for (int it = 0; it < 4; ++it) {
        int e = it * 256 + threadIdx.x;
        ((float*)tile)[e] = in[base + e];
    }
    __syncthreads();
    int ri = threadIdx.x >> 6;                 // row 0..3
    int k = threadIdx.x & 63;                  // float4 chunk index
    const float4* row4 = (const float4*)tile[ri];
    float w[36];
#pragma unroll
    for (int j = 0; j < 9; ++j) {
        float4 q = row4[(k - 4 + j) & 63];
        w[4 * j + 0] = q.x; w[4 * j + 1] = q.y; w[4 * j + 2] = q.z; w[4 * j + 3] = q.w;
    }
    float acc[4] = {0.f, 0.f, 0.f, 0.f};
#pragma unroll
    for (int kk = 0; kk < 36; ++kk) {
#pragma unroll
        for (int i = 0; i < 4; ++i) {
            int d = kk - 16 - i;
            if (d >= -16 && d <= 16) acc[i] = fmaf(shv[d < 0 ? -d : d], w[kk], acc[i]);
        }
    }
    ((float4*)out)[(size_t)bx * 256 + ri * 64 + k] = make_float4(acc[0], acc[1], acc[2], acc[3]);
}

// ---------------------------------------------------------------------------
extern "C" void kernel_launch(void* const* d_in, const int* in_sizes, int n_in,
                              void* d_out, int out_size, void* d_ws, size_t ws_size,
                              hipStream_t stream) {
    const float* means   = (const float*)d_in[0];
    const float* weights = (const float*)d_in[1];
    const float* sigma   = (const float*)d_in[2];
    int n = in_sizes[1];                        // 500000 points

    float* vol = (float*)d_ws;                  // 64 MB scratch volume
    float* h   = (float*)((char*)d_ws + VOLBYTES);
    float* out = (float*)d_out;

    // scratch metadata in d_out (all dead before conv_d0 overwrites d_out)
    char* ob = (char*)d_out;
    float4*   sorted    = (float4*)ob;                                   // 8 MB
    unsigned* cellcnt   = (unsigned*)(ob + (8u << 20));                  // 16 KB
    unsigned* cellstart = (unsigned*)(ob + (8u << 20) + 65536);          // 16 KB
    unsigned* cursor    = (unsigned*)(ob + (8u << 20) + 131072);         // 16 KB

    hipMemsetAsync(vol, 0, VOLBYTES, stream);
    hipMemsetAsync(cellcnt, 0, CELLS * sizeof(unsigned), stream);
    taps_kernel<<<1, 256, 0, stream>>>(sigma, h);

    int nb = (n + HB * PPT - 1) / (HB * PPT);
    hist_kernel<<<nb, HB, 0, stream>>>(means, cellcnt, n);
    scan_kernel<<<1, 1024, 0, stream>>>(cellcnt, cellstart, cursor);
    scatter_kernel<<<nb, HB, 0, stream>>>(means, weights, cursor, sorted, n);
    cellsplat_kernel<<<CELLS, 256, 0, stream>>>(sorted, cellstart, vol, n);

    conv_d0_kernel<<<dim3(256, 4, 2), 256, 0, stream>>>(vol, out, h);   // blur dim0
    conv_d1_kernel<<<dim3(256, 4, 2), 256, 0, stream>>>(out, vol, h);   // blur dim1
    conv_d2_kernel<<<16384, 256, 0, stream>>>(vol, out, h);             // blur dim2
}

// Round 10
// 865.507 us; speedup vs baseline: 1.6400x; 1.6400x over previous
//
#include <hip/hip_runtime.h>
#include <math.h>

#define GN 256
#define VOLN (GN * GN * GN)
#define VOLBYTES ((size_t)VOLN * sizeof(float))
#define RAD 16          // truncation radius of the exact circular-conv kernel

// spatial cells: 16^3 voxels per cell, 16^3 = 4096 cells
#define CELLW 16
#define CPA   16
#define CELLS (CPA * CPA * CPA)
#define TILEW (CELLW + 1)                 // 17
#define TILEN (TILEW * TILEW * TILEW)     // 4913

#define HB  512         // threads per hist/scatter block
#define PPT 2           // points per thread
#define CHUNK 2048      // max points per cellsplat block
#define MAXCHUNKS 4352  // >= 4096 (1/cell) + 500000/2048 (+slack)

__device__ __forceinline__ int cell_of(float g0, float g1, float g2) {
    int b0 = (int)floorf(g0), b1 = (int)floorf(g1), b2 = (int)floorf(g2);
    b0 = min(max(b0, 0), 255); b1 = min(max(b1, 0), 255); b2 = min(max(b2, 0), 255);
    return ((b0 >> 4) << 8) | ((b1 >> 4) << 4) | (b2 >> 4);
}

// ---------------------------------------------------------------------------
// Pass 1: per-block LDS histogram. 489 blocks; merge only non-zero cells.
// ---------------------------------------------------------------------------
__global__ __launch_bounds__(HB) void hist_kernel(const float* __restrict__ means,
                                                  unsigned* __restrict__ cellcnt, int n) {
    __shared__ unsigned lh[CELLS];
    int t = threadIdx.x;
    for (int i = t; i < CELLS; i += HB) lh[i] = 0u;
    __syncthreads();
    int base = blockIdx.x * (HB * PPT);
    for (int j = 0; j < PPT; ++j) {
        int p = base + j * HB + t;
        if (p < n) {
            float g0 = fmaf(means[3 * p + 0], 128.f, 128.f);
            float g1 = fmaf(means[3 * p + 1], 128.f, 128.f);
            float g2 = fmaf(means[3 * p + 2], 128.f, 128.f);
            atomicAdd(&lh[cell_of(g0, g1, g2)], 1u);
        }
    }
    __syncthreads();
    for (int i = t; i < CELLS; i += HB) {
        unsigned v = lh[i];
        if (v) atomicAdd(&cellcnt[i], v);
    }
}

// ---------------------------------------------------------------------------
// Pass 2: scan of cell counts -> cellstart/cursor; second scan over
// chunk counts -> chunk descriptors {cell, start, end} (<=CHUNK points each);
// sentinel-fill the rest of desc[].
// ---------------------------------------------------------------------------
__global__ __launch_bounds__(1024) void scan_kernel(const unsigned* __restrict__ cellcnt,
                                                    unsigned* __restrict__ cellstart,
                                                    unsigned* __restrict__ cursor,
                                                    uint4* __restrict__ desc) {
    __shared__ unsigned sums[1024];
    int t = threadIdx.x;
    unsigned c[4], loc[4], tot = 0u;
#pragma unroll
    for (int i = 0; i < 4; ++i) { c[i] = cellcnt[t * 4 + i]; loc[i] = tot; tot += c[i]; }
    sums[t] = tot;
    __syncthreads();
    for (int ofs = 1; ofs < 1024; ofs <<= 1) {
        unsigned v = (t >= ofs) ? sums[t - ofs] : 0u;
        __syncthreads();
        sums[t] += v;
        __syncthreads();
    }
    unsigned base = (t == 0) ? 0u : sums[t - 1];
    unsigned cs[4];
#pragma unroll
    for (int i = 0; i < 4; ++i) {
        cs[i] = base + loc[i];
        cellstart[t * 4 + i] = cs[i];
        cursor[t * 4 + i] = cs[i];
    }
    // ---- second scan: chunks per cell ----
    unsigned nch[4], lch[4], ctot = 0u;
#pragma unroll
    for (int i = 0; i < 4; ++i) { nch[i] = (c[i] + CHUNK - 1) / CHUNK; lch[i] = ctot; ctot += nch[i]; }
    __syncthreads();
    sums[t] = ctot;
    __syncthreads();
    for (int ofs = 1; ofs < 1024; ofs <<= 1) {
        unsigned v = (t >= ofs) ? sums[t - ofs] : 0u;
        __syncthreads();
        sums[t] += v;
        __syncthreads();
    }
    unsigned cbase = (t == 0) ? 0u : sums[t - 1];
#pragma unroll
    for (int i = 0; i < 4; ++i) {
        unsigned cb = cbase + lch[i];
        for (unsigned k = 0; k < nch[i]; ++k) {
            unsigned s0 = cs[i] + k * CHUNK;
            unsigned s1 = min(s0 + CHUNK, cs[i] + c[i]);
            desc[cb + k] = make_uint4((unsigned)(t * 4 + i), s0, s1, 0u);
        }
    }
    __syncthreads();
    unsigned total = sums[1023];
    for (unsigned i = total + t; i < MAXCHUNKS; i += 1024)
        desc[i] = make_uint4(0xFFFFFFFFu, 0u, 0u, 0u);
}

// ---------------------------------------------------------------------------
// Pass 3: 3-phase scatter (LDS count -> global reserve -> ranked placement).
// ---------------------------------------------------------------------------
__global__ __launch_bounds__(HB) void scatter_kernel(const float* __restrict__ means,
                                                     const float* __restrict__ weights,
                                                     unsigned* __restrict__ cursor,
                                                     float4* __restrict__ sorted, int n) {
    __shared__ unsigned lh[CELLS];
    int t = threadIdx.x;
    for (int i = t; i < CELLS; i += HB) lh[i] = 0u;
    __syncthreads();
    int base = blockIdx.x * (HB * PPT);
    for (int j = 0; j < PPT; ++j) {
        int p = base + j * HB + t;
        if (p < n) {
            float g0 = fmaf(means[3 * p + 0], 128.f, 128.f);
            float g1 = fmaf(means[3 * p + 1], 128.f, 128.f);
            float g2 = fmaf(means[3 * p + 2], 128.f, 128.f);
            atomicAdd(&lh[cell_of(g0, g1, g2)], 1u);
        }
    }
    __syncthreads();
    for (int i = t; i < CELLS; i += HB) {
        unsigned v = lh[i];
        lh[i] = v ? atomicAdd(&cursor[i], v) : 0u;   // lh now holds block's base
    }
    __syncthreads();
    for (int j = 0; j < PPT; ++j) {
        int p = base + j * HB + t;
        if (p < n) {
            float g0 = fmaf(means[3 * p + 0], 128.f, 128.f);
            float g1 = fmaf(means[3 * p + 1], 128.f, 128.f);
            float g2 = fmaf(means[3 * p + 2], 128.f, 128.f);
            unsigned pos = atomicAdd(&lh[cell_of(g0, g1, g2)], 1u);
            sorted[pos] = make_float4(g0, g1, g2, fmaxf(weights[p], 0.f));
        }
    }
}

// ---------------------------------------------------------------------------
// Pass 4: one block per CHUNK (load-balanced). Splat <=2048 points into a
// 17^3 LDS tile, then atomicAdd the non-zero tile entries to the volume
// (coalesced addresses). OOB corners dropped (JAX scatter semantics).
// ---------------------------------------------------------------------------
__global__ __launch_bounds__(256) void cellsplat_kernel(const float4* __restrict__ sorted,
                                                        const uint4* __restrict__ desc,
                                                        float* __restrict__ vol) {
    __shared__ float tile[TILEN];
    uint4 d = desc[blockIdx.x];
    if (d.x == 0xFFFFFFFFu) return;            // sentinel: unused block
    int c = (int)d.x;
    unsigned start = d.y, end = d.z;
    for (int i = threadIdx.x; i < TILEN; i += 256) tile[i] = 0.f;
    __syncthreads();
    int cb0 = (c >> 8) << 4, cb1 = ((c >> 4) & 15) << 4, cb2 = (c & 15) << 4;
    for (unsigned p0 = start; p0 < end; p0 += 256) {
        unsigned p = p0 + threadIdx.x;
        if (p < end) {
            float4 q = sorted[p];
            float f0 = floorf(q.x), f1 = floorf(q.y), f2 = floorf(q.z);
            int b0 = (int)f0, b1 = (int)f1, b2 = (int)f2;
            float r0 = q.x - f0, r1 = q.y - f1, r2 = q.z - f2;
            float c0v[2] = {1.f - r0, r0}, c1v[2] = {1.f - r1, r1}, c2v[2] = {1.f - r2, r2};
#pragma unroll
            for (int o0 = 0; o0 < 2; ++o0) {
                int v0 = b0 + o0, t0 = v0 - cb0;
                if ((unsigned)t0 > 16u || (unsigned)v0 > 255u) continue;
#pragma unroll
                for (int o1 = 0; o1 < 2; ++o1) {
                    int v1 = b1 + o1, t1 = v1 - cb1;
                    if ((unsigned)t1 > 16u || (unsigned)v1 > 255u) continue;
                    float w01 = c0v[o0] * c1v[o1] * q.w;
#pragma unroll
                    for (int o2 = 0; o2 < 2; ++o2) {
                        int v2 = b2 + o2, t2 = v2 - cb2;
                        if ((unsigned)t2 > 16u || (unsigned)v2 > 255u) continue;
                        atomicAdd(&tile[t0 * (TILEW * TILEW) + t1 * TILEW + t2], w01 * c2v[o2]);
                    }
                }
            }
        }
    }
    __syncthreads();
    for (int i = threadIdx.x; i < TILEN; i += 256) {
        float val = tile[i];
        if (val == 0.f) continue;
        int t0 = i / (TILEW * TILEW);
        int rem = i - t0 * (TILEW * TILEW);
        int t1 = rem / TILEW, t2 = rem - t1 * TILEW;
        int v0 = cb0 + t0, v1 = cb1 + t1, v2 = cb2 + t2;
        if (v0 < 256 && v1 < 256 && v2 < 256)
            atomicAdd(&vol[(v0 << 16) | (v1 << 8) | v2], val);
    }
}

// ---------------------------------------------------------------------------
// Exact 1-D blur taps (parallel DFT sum): h[m] = (1/256) * sum_k
//   exp(-2 pi^2 sigma^2 f_k^2) * cos(2 pi k m / 256)
// ---------------------------------------------------------------------------
__global__ __launch_bounds__(256) void taps_kernel(const float* __restrict__ sigma_param,
                                                   float* __restrict__ h) {
    __shared__ float red[4];
    int k = threadIdx.x;
    float s = fmaxf(sigma_param[0], 0.f);
    int kk = (k < 128) ? k : k - 256;
    float f = (float)kk / 256.f;
    float cc = 2.f * (float)(M_PI * M_PI) * s * s;
    float term = expf(-cc * f * f);
    int wid = k >> 6, lane = k & 63;
    for (int m = 0; m <= RAD; ++m) {
        int idx = (k * m) & 255;
        float v = term * cosf((float)idx * (2.f * (float)M_PI / 256.f));
#pragma unroll
        for (int o = 32; o > 0; o >>= 1) v += __shfl_down(v, o, 64);
        if (lane == 0) red[wid] = v;
        __syncthreads();
        if (k == 0) h[m] = (red[0] + red[1] + red[2] + red[3]) * (1.f / 256.f);
        __syncthreads();
    }
}

// ---------------------------------------------------------------------------
// Separable circular convolutions, LDS-tiled + register-windowed.
// Volume index: (i0<<16)|(i1<<8)|i2, i2 contiguous.
// ---------------------------------------------------------------------------
__global__ __launch_bounds__(256) void conv_d0_kernel(const float* __restrict__ in,
                                                      float* __restrict__ out,
                                                      const float* __restrict__ h) {
    __shared__ float tile[96][128];
    float shv[17];
#pragma unroll
    for (int j = 0; j < 17; ++j) shv[j] = h[j];
    int i1 = blockIdx.x, t0 = blockIdx.y, ch = blockIdx.z;
    int colbase = ch << 7;
#pragma unroll
    for (int it = 0; it < 48; ++it) {
        int e = it * 256 + threadIdx.x;
        int r = e >> 7, cc = e & 127;
        int i0 = ((t0 << 6) + r - 16) & 255;
        tile[r][cc] = in[(i0 << 16) | (i1 << 8) | (colbase + cc)];
    }
    __syncthreads();
    int c = threadIdx.x & 127;
    int ob = (threadIdx.x >> 7) << 5;        // 0 or 32
    float acc[32];
#pragma unroll
    for (int j = 0; j < 32; ++j) acc[j] = 0.f;
#pragma unroll
    for (int rr = 0; rr < 64; ++rr) {
        float v = tile[ob + rr][c];
#pragma unroll
        for (int jj = 0; jj < 32; ++jj) {
            int d = rr - jj - 16;
            if (d >= -16 && d <= 16) acc[jj] = fmaf(shv[d < 0 ? -d : d], v, acc[jj]);
        }
    }
    int o0base = (t0 << 6) + ob;
#pragma unroll
    for (int jj = 0; jj < 32; ++jj)
        out[((o0base + jj) << 16) | (i1 << 8) | (colbase + c)] = acc[jj];
}

__global__ __launch_bounds__(256) void conv_d1_kernel(const float* __restrict__ in,
                                                      float* __restrict__ out,
                                                      const float* __restrict__ h) {
    __shared__ float tile[96][128];
    float shv[17];
#pragma unroll
    for (int j = 0; j < 17; ++j) shv[j] = h[j];
    int i0 = blockIdx.x, t1 = blockIdx.y, ch = blockIdx.z;
    int colbase = ch << 7;
#pragma unroll
    for (int it = 0; it < 48; ++it) {
        int e = it * 256 + threadIdx.x;
        int r = e >> 7, cc = e & 127;
        int i1 = ((t1 << 6) + r - 16) & 255;
        tile[r][cc] = in[(i0 << 16) | (i1 << 8) | (colbase + cc)];
    }
    __syncthreads();
    int c = threadIdx.x & 127;
    int ob = (threadIdx.x >> 7) << 5;
    float acc[32];
#pragma unroll
    for (int j = 0; j < 32; ++j) acc[j] = 0.f;
#pragma unroll
    for (int rr = 0; rr < 64; ++rr) {
        float v = tile[ob + rr][c];
#pragma unroll
        for (int jj = 0; jj < 32; ++jj) {
            int d = rr - jj - 16;
            if (d >= -16 && d <= 16) acc[jj] = fmaf(shv[d < 0 ? -d : d], v, acc[jj]);
        }
    }
    int o1base = (t1 << 6) + ob;
#pragma unroll
    for (int jj = 0; jj < 32; ++jj)
        out[(i0 << 16) | ((o1base + jj) << 8) | (colbase + c)] = acc[jj];
}

__global__ __launch_bounds__(256) void conv_d2_kernel(const float* __restrict__ in,
                                                      float* __restrict__ out,
                                                      const float* __restrict__ h) {
    __shared__ float tile[4][256];
    float shv[17];
#pragma unroll
    for (int j = 0; j < 17; ++j) shv[j] = h[j];
    int bx = blockIdx.x;                       // 16384 blocks
    size_t base = (size_t)bx * 1024;
#pragma unroll
    for (int it = 0; it < 4; ++it) {
        int e = it * 256 + threadIdx.x;
        ((float*)tile)[e] = in[base + e];
    }
    __syncthreads();
    int ri = threadIdx.x >> 6;                 // row 0..3
    int k = threadIdx.x & 63;                  // float4 chunk index
    const float4* row4 = (const float4*)tile[ri];
    float w[36];
#pragma unroll
    for (int j = 0; j < 9; ++j) {
        float4 q = row4[(k - 4 + j) & 63];
        w[4 * j + 0] = q.x; w[4 * j + 1] = q.y; w[4 * j + 2] = q.z; w[4 * j + 3] = q.w;
    }
    float acc[4] = {0.f, 0.f, 0.f, 0.f};
#pragma unroll
    for (int kk = 0; kk < 36; ++kk) {
#pragma unroll
        for (int i = 0; i < 4; ++i) {
            int d = kk - 16 - i;
            if (d >= -16 && d <= 16) acc[i] = fmaf(shv[d < 0 ? -d : d], w[kk], acc[i]);
        }
    }
    ((float4*)out)[(size_t)bx * 256 + ri * 64 + k] = make_float4(acc[0], acc[1], acc[2], acc[3]);
}

// ---------------------------------------------------------------------------
extern "C" void kernel_launch(void* const* d_in, const int* in_sizes, int n_in,
                              void* d_out, int out_size, void* d_ws, size_t ws_size,
                              hipStream_t stream) {
    const float* means   = (const float*)d_in[0];
    const float* weights = (const float*)d_in[1];
    const float* sigma   = (const float*)d_in[2];
    int n = in_sizes[1];                        // 500000 points

    float* vol = (float*)d_ws;                  // 64 MB scratch volume
    float* h   = (float*)((char*)d_ws + VOLBYTES);
    float* out = (float*)d_out;

    // scratch metadata in d_out (all dead before conv_d0 overwrites d_out)
    char* ob = (char*)d_out;
    float4*   sorted    = (float4*)ob;                                   // 8 MB
    unsigned* cellcnt   = (unsigned*)(ob + (8u << 20));                  // 16 KB
    unsigned* cellstart = (unsigned*)(ob + (8u << 20) + 65536);          // 16 KB
    unsigned* cursor    = (unsigned*)(ob + (8u << 20) + 131072);         // 16 KB
    uint4*    desc      = (uint4*)(ob + (9u << 20));                     // 68 KB

    hipMemsetAsync(vol, 0, VOLBYTES, stream);
    hipMemsetAsync(cellcnt, 0, CELLS * sizeof(unsigned), stream);
    taps_kernel<<<1, 256, 0, stream>>>(sigma, h);

    int nb = (n + HB * PPT - 1) / (HB * PPT);   // 489 blocks
    hist_kernel<<<nb, HB, 0, stream>>>(means, cellcnt, n);
    scan_kernel<<<1, 1024, 0, stream>>>(cellcnt, cellstart, cursor, desc);
    scatter_kernel<<<nb, HB, 0, stream>>>(means, weights, cursor, sorted, n);
    cellsplat_kernel<<<MAXCHUNKS, 256, 0, stream>>>(sorted, desc, vol);

    conv_d0_kernel<<<dim3(256, 4, 2), 256, 0, stream>>>(vol, out, h);   // blur dim0
    conv_d1_kernel<<<dim3(256, 4, 2), 256, 0, stream>>>(out, vol, h);   // blur dim1
    conv_d2_kernel<<<16384, 256, 0, stream>>>(vol, out, h);             // blur dim2
}

// Round 12
// 244.852 us; speedup vs baseline: 5.7972x; 3.5348x over previous
//
#include <hip/hip_runtime.h>
#include <math.h>

#define GN 256
#define VOLN (GN * GN * GN)
#define VOLBYTES ((size_t)VOLN * sizeof(float))
#define RAD 16          // truncation radius of the exact circular-conv kernel

// spatial cells: 16^3 voxels per cell, 16^3 = 4096 cells
#define CELLW 16
#define CPA   16
#define CELLS (CPA * CPA * CPA)
#define TILEW (CELLW + 1)                 // 17
#define TILEN (TILEW * TILEW * TILEW)     // 4913

#define HB  512         // threads per hist/scatter block
#define PPT 2           // points per thread
#define CHUNK 2048      // max points per cellsplat block
#define MAXCHUNKS 4352  // >= 4096 (1/cell) + 500000/2048 (+slack)

#define CCH 16          // float4 per conv col-chunk (64 floats)

__device__ __forceinline__ int cell_of(float g0, float g1, float g2) {
    int b0 = (int)floorf(g0), b1 = (int)floorf(g1), b2 = (int)floorf(g2);
    b0 = min(max(b0, 0), 255); b1 = min(max(b1, 0), 255); b2 = min(max(b2, 0), 255);
    return ((b0 >> 4) << 8) | ((b1 >> 4) << 4) | (b2 >> 4);
}

// ---------------------------------------------------------------------------
// Pass 1: per-block LDS histogram.
// ---------------------------------------------------------------------------
__global__ __launch_bounds__(HB) void hist_kernel(const float* __restrict__ means,
                                                  unsigned* __restrict__ cellcnt, int n) {
    __shared__ unsigned lh[CELLS];
    int t = threadIdx.x;
    for (int i = t; i < CELLS; i += HB) lh[i] = 0u;
    __syncthreads();
    int base = blockIdx.x * (HB * PPT);
    for (int j = 0; j < PPT; ++j) {
        int p = base + j * HB + t;
        if (p < n) {
            float g0 = fmaf(means[3 * p + 0], 128.f, 128.f);
            float g1 = fmaf(means[3 * p + 1], 128.f, 128.f);
            float g2 = fmaf(means[3 * p + 2], 128.f, 128.f);
            atomicAdd(&lh[cell_of(g0, g1, g2)], 1u);
        }
    }
    __syncthreads();
    for (int i = t; i < CELLS; i += HB) {
        unsigned v = lh[i];
        if (v) atomicAdd(&cellcnt[i], v);
    }
}

// ---------------------------------------------------------------------------
// Pass 2: scan of cell counts -> cellstart/cursor; second scan over chunk
// counts -> chunk descriptors {cell, start, end}; sentinel-fill the rest.
// ---------------------------------------------------------------------------
__global__ __launch_bounds__(1024) void scan_kernel(const unsigned* __restrict__ cellcnt,
                                                    unsigned* __restrict__ cellstart,
                                                    unsigned* __restrict__ cursor,
                                                    uint4* __restrict__ desc) {
    __shared__ unsigned sums[1024];
    int t = threadIdx.x;
    unsigned c[4], loc[4], tot = 0u;
#pragma unroll
    for (int i = 0; i < 4; ++i) { c[i] = cellcnt[t * 4 + i]; loc[i] = tot; tot += c[i]; }
    sums[t] = tot;
    __syncthreads();
    for (int ofs = 1; ofs < 1024; ofs <<= 1) {
        unsigned v = (t >= ofs) ? sums[t - ofs] : 0u;
        __syncthreads();
        sums[t] += v;
        __syncthreads();
    }
    unsigned base = (t == 0) ? 0u : sums[t - 1];
    unsigned cs[4];
#pragma unroll
    for (int i = 0; i < 4; ++i) {
        cs[i] = base + loc[i];
        cellstart[t * 4 + i] = cs[i];
        cursor[t * 4 + i] = cs[i];
    }
    // ---- second scan: chunks per cell ----
    unsigned nch[4], lch[4], ctot = 0u;
#pragma unroll
    for (int i = 0; i < 4; ++i) { nch[i] = (c[i] + CHUNK - 1) / CHUNK; lch[i] = ctot; ctot += nch[i]; }
    __syncthreads();
    sums[t] = ctot;
    __syncthreads();
    for (int ofs = 1; ofs < 1024; ofs <<= 1) {
        unsigned v = (t >= ofs) ? sums[t - ofs] : 0u;
        __syncthreads();
        sums[t] += v;
        __syncthreads();
    }
    unsigned cbase = (t == 0) ? 0u : sums[t - 1];
#pragma unroll
    for (int i = 0; i < 4; ++i) {
        unsigned cb = cbase + lch[i];
        for (unsigned k = 0; k < nch[i]; ++k) {
            unsigned s0 = cs[i] + k * CHUNK;
            unsigned s1 = min(s0 + CHUNK, cs[i] + c[i]);
            desc[cb + k] = make_uint4((unsigned)(t * 4 + i), s0, s1, 0u);
        }
    }
    __syncthreads();
    unsigned total = sums[1023];
    for (unsigned i = total + t; i < MAXCHUNKS; i += 1024)
        desc[i] = make_uint4(0xFFFFFFFFu, 0u, 0u, 0u);
}

// ---------------------------------------------------------------------------
// Pass 3: 3-phase scatter (LDS count -> global reserve -> ranked placement).
// ---------------------------------------------------------------------------
__global__ __launch_bounds__(HB) void scatter_kernel(const float* __restrict__ means,
                                                     const float* __restrict__ weights,
                                                     unsigned* __restrict__ cursor,
                                                     float4* __restrict__ sorted, int n) {
    __shared__ unsigned lh[CELLS];
    int t = threadIdx.x;
    for (int i = t; i < CELLS; i += HB) lh[i] = 0u;
    __syncthreads();
    int base = blockIdx.x * (HB * PPT);
    for (int j = 0; j < PPT; ++j) {
        int p = base + j * HB + t;
        if (p < n) {
            float g0 = fmaf(means[3 * p + 0], 128.f, 128.f);
            float g1 = fmaf(means[3 * p + 1], 128.f, 128.f);
            float g2 = fmaf(means[3 * p + 2], 128.f, 128.f);
            atomicAdd(&lh[cell_of(g0, g1, g2)], 1u);
        }
    }
    __syncthreads();
    for (int i = t; i < CELLS; i += HB) {
        unsigned v = lh[i];
        lh[i] = v ? atomicAdd(&cursor[i], v) : 0u;   // lh now holds block's base
    }
    __syncthreads();
    for (int j = 0; j < PPT; ++j) {
        int p = base + j * HB + t;
        if (p < n) {
            float g0 = fmaf(means[3 * p + 0], 128.f, 128.f);
            float g1 = fmaf(means[3 * p + 1], 128.f, 128.f);
            float g2 = fmaf(means[3 * p + 2], 128.f, 128.f);
            unsigned pos = atomicAdd(&lh[cell_of(g0, g1, g2)], 1u);
            sorted[pos] = make_float4(g0, g1, g2, fmaxf(weights[p], 0.f));
        }
    }
}

// ---------------------------------------------------------------------------
// Pass 4: one block per CHUNK (load-balanced). Splat <=2048 points into a
// 17^3 LDS tile, then atomicAdd non-zero entries (coalesced addresses).
// ---------------------------------------------------------------------------
__global__ __launch_bounds__(256) void cellsplat_kernel(const float4* __restrict__ sorted,
                                                        const uint4* __restrict__ desc,
                                                        float* __restrict__ vol) {
    __shared__ float tile[TILEN];
    uint4 d = desc[blockIdx.x];
    if (d.x == 0xFFFFFFFFu) return;            // sentinel: unused block
    int c = (int)d.x;
    unsigned start = d.y, end = d.z;
    for (int i = threadIdx.x; i < TILEN; i += 256) tile[i] = 0.f;
    __syncthreads();
    int cb0 = (c >> 8) << 4, cb1 = ((c >> 4) & 15) << 4, cb2 = (c & 15) << 4;
    for (unsigned p0 = start; p0 < end; p0 += 256) {
        unsigned p = p0 + threadIdx.x;
        if (p < end) {
            float4 q = sorted[p];
            float f0 = floorf(q.x), f1 = floorf(q.y), f2 = floorf(q.z);
            int b0 = (int)f0, b1 = (int)f1, b2 = (int)f2;
            float r0 = q.x - f0, r1 = q.y - f1, r2 = q.z - f2;
            float c0v[2] = {1.f - r0, r0}, c1v[2] = {1.f - r1, r1}, c2v[2] = {1.f - r2, r2};
#pragma unroll
            for (int o0 = 0; o0 < 2; ++o0) {
                int v0 = b0 + o0, t0 = v0 - cb0;
                if ((unsigned)t0 > 16u || (unsigned)v0 > 255u) continue;
#pragma unroll
                for (int o1 = 0; o1 < 2; ++o1) {
                    int v1 = b1 + o1, t1 = v1 - cb1;
                    if ((unsigned)t1 > 16u || (unsigned)v1 > 255u) continue;
                    float w01 = c0v[o0] * c1v[o1] * q.w;
#pragma unroll
                    for (int o2 = 0; o2 < 2; ++o2) {
                        int v2 = b2 + o2, t2 = v2 - cb2;
                        if ((unsigned)t2 > 16u || (unsigned)v2 > 255u) continue;
                        atomicAdd(&tile[t0 * (TILEW * TILEW) + t1 * TILEW + t2], w01 * c2v[o2]);
                    }
                }
            }
        }
    }
    __syncthreads();
    for (int i = threadIdx.x; i < TILEN; i += 256) {
        float val = tile[i];
        if (val == 0.f) continue;
        int t0 = i / (TILEW * TILEW);
        int rem = i - t0 * (TILEW * TILEW);
        int t1 = rem / TILEW, t2 = rem - t1 * TILEW;
        int v0 = cb0 + t0, v1 = cb1 + t1, v2 = cb2 + t2;
        if (v0 < 256 && v1 < 256 && v2 < 256)
            atomicAdd(&vol[(v0 << 16) | (v1 << 8) | v2], val);
    }
}

// ---------------------------------------------------------------------------
// Exact 1-D blur taps (parallel DFT sum).
// ---------------------------------------------------------------------------
__global__ __launch_bounds__(256) void taps_kernel(const float* __restrict__ sigma_param,
                                                   float* __restrict__ h) {
    __shared__ float red[4];
    int k = threadIdx.x;
    float s = fmaxf(sigma_param[0], 0.f);
    int kk = (k < 128) ? k : k - 256;
    float f = (float)kk / 256.f;
    float cc = 2.f * (float)(M_PI * M_PI) * s * s;
    float term = expf(-cc * f * f);
    int wid = k >> 6, lane = k & 63;
    for (int m = 0; m <= RAD; ++m) {
        int idx = (k * m) & 255;
        float v = term * cosf((float)idx * (2.f * (float)M_PI / 256.f));
#pragma unroll
        for (int o = 32; o > 0; o >>= 1) v += __shfl_down(v, o, 64);
        if (lane == 0) red[wid] = v;
        __syncthreads();
        if (k == 0) h[m] = (red[0] + red[1] + red[2] + red[3]) * (1.f / 256.f);
        __syncthreads();
    }
}

// ---------------------------------------------------------------------------
// Separable circular convolutions. ALL register-array indices compile-time;
// the 33-tap window is read directly from LDS as float4 (runtime base +
// constant offset folds into ds_read_b128 offset:N). Volume index:
// float4 idx = (i0<<14)|(i1<<6)|col4.
// ---------------------------------------------------------------------------
__global__ __launch_bounds__(256) void conv_d0_kernel(const float* __restrict__ in,
                                                      float* __restrict__ out,
                                                      const float* __restrict__ hh) {
    __shared__ float4 tile4[96][CCH];          // 24 KB
    float shv[17];
#pragma unroll
    for (int j = 0; j < 17; ++j) shv[j] = hh[j];
    float taps[33];
#pragma unroll
    for (int m = 0; m < 33; ++m) taps[m] = shv[m < 16 ? 16 - m : m - 16];
    int i1 = blockIdx.x, t0 = blockIdx.y, ch = blockIdx.z;
    int colbase4 = ch * CCH;
    const float4* in4 = (const float4*)in;
#pragma unroll
    for (int it = 0; it < (96 * CCH) / 256; ++it) {   // 6 iters
        int e = it * 256 + threadIdx.x;
        int r = e / CCH, cc = e % CCH;
        int i0 = ((t0 << 6) + r - 16) & 255;
        tile4[r][cc] = in4[(i0 << 14) | (i1 << 6) | (colbase4 + cc)];
    }
    __syncthreads();
    int cg = threadIdx.x & (CCH - 1);
    int r0 = threadIdx.x / CCH;                // 0..15
    for (int ro = 0; ro < 4; ++ro) {
        int rr = r0 + ro * 16;                 // output row offset 0..63
        float4 acc = make_float4(0.f, 0.f, 0.f, 0.f);
#pragma unroll
        for (int m = 0; m < 33; ++m) {
            float4 v = tile4[rr + m][cg];
            acc.x = fmaf(taps[m], v.x, acc.x);
            acc.y = fmaf(taps[m], v.y, acc.y);
            acc.z = fmaf(taps[m], v.z, acc.z);
            acc.w = fmaf(taps[m], v.w, acc.w);
        }
        int o0 = (t0 << 6) + rr;
        ((float4*)out)[(o0 << 14) | (i1 << 6) | (colbase4 + cg)] = acc;
    }
}

__global__ __launch_bounds__(256) void conv_d1_kernel(const float* __restrict__ in,
                                                      float* __restrict__ out,
                                                      const float* __restrict__ hh) {
    __shared__ float4 tile4[96][CCH];
    float shv[17];
#pragma unroll
    for (int j = 0; j < 17; ++j) shv[j] = hh[j];
    float taps[33];
#pragma unroll
    for (int m = 0; m < 33; ++m) taps[m] = shv[m < 16 ? 16 - m : m - 16];
    int i0 = blockIdx.x, t1 = blockIdx.y, ch = blockIdx.z;
    int colbase4 = ch * CCH;
    const float4* in4 = (const float4*)in;
#pragma unroll
    for (int it = 0; it < (96 * CCH) / 256; ++it) {
        int e = it * 256 + threadIdx.x;
        int r = e / CCH, cc = e % CCH;
        int i1 = ((t1 << 6) + r - 16) & 255;
        tile4[r][cc] = in4[(i0 << 14) | (i1 << 6) | (colbase4 + cc)];
    }
    __syncthreads();
    int cg = threadIdx.x & (CCH - 1);
    int r0 = threadIdx.x / CCH;
    for (int ro = 0; ro < 4; ++ro) {
        int rr = r0 + ro * 16;
        float4 acc = make_float4(0.f, 0.f, 0.f, 0.f);
#pragma unroll
        for (int m = 0; m < 33; ++m) {
            float4 v = tile4[rr + m][cg];
            acc.x = fmaf(taps[m], v.x, acc.x);
            acc.y = fmaf(taps[m], v.y, acc.y);
            acc.z = fmaf(taps[m], v.z, acc.z);
            acc.w = fmaf(taps[m], v.w, acc.w);
        }
        int o1 = (t1 << 6) + rr;
        ((float4*)out)[(i0 << 14) | (o1 << 6) | (colbase4 + cg)] = acc;
    }
}

// conv along i2 (contiguous): unchanged (was not a bottleneck).
__global__ __launch_bounds__(256) void conv_d2_kernel(const float* __restrict__ in,
                                                      float* __restrict__ out,
                                                      const float* __restrict__ hh) {
    __shared__ float tile[4][256];
    float shv[17];
#pragma unroll
    for (int j = 0; j < 17; ++j) shv[j] = hh[j];
    int bx = blockIdx.x;                       // 16384 blocks
    size_t base = (size_t)bx * 1024;
#pragma unroll
    for (int it = 0; it < 4; ++it) {
        int e = it * 256 + threadIdx.x;
        ((float*)tile)[e] = in[base + e];
    }
    __syncthreads();
    int ri = threadIdx.x >> 6;                 // row 0..3
    int k = threadIdx.x & 63;                  // float4 chunk index
    const float4* row4 = (const float4*)tile[ri];
    float w[36];
#pragma unroll
    for (int j = 0; j < 9; ++j) {
        float4 q = row4[(k - 4 + j) & 63];
        w[4 * j + 0] = q.x; w[4 * j + 1] = q.y; w[4 * j + 2] = q.z; w[4 * j + 3] = q.w;
    }
    float acc[4] = {0.f, 0.f, 0.f, 0.f};
#pragma unroll
    for (int kk = 0; kk < 36; ++kk) {
#pragma unroll
        for (int i = 0; i < 4; ++i) {
            int d = kk - 16 - i;
            if (d >= -16 && d <= 16) acc[i] = fmaf(shv[d < 0 ? -d : d], w[kk], acc[i]);
        }
    }
    ((float4*)out)[(size_t)bx * 256 + ri * 64 + k] = make_float4(acc[0], acc[1], acc[2], acc[3]);
}

// ---------------------------------------------------------------------------
extern "C" void kernel_launch(void* const* d_in, const int* in_sizes, int n_in,
                              void* d_out, int out_size, void* d_ws, size_t ws_size,
                              hipStream_t stream) {
    const float* means   = (const float*)d_in[0];
    const float* weights = (const float*)d_in[1];
    const float* sigma   = (const float*)d_in[2];
    int n = in_sizes[1];                        // 500000 points

    float* vol = (float*)d_ws;                  // 64 MB scratch volume
    float* h   = (float*)((char*)d_ws + VOLBYTES);
    float* out = (float*)d_out;

    // scratch metadata in d_out (all dead before conv_d0 overwrites d_out)
    char* ob = (char*)d_out;
    float4*   sorted    = (float4*)ob;                                   // 8 MB
    unsigned* cellcnt   = (unsigned*)(ob + (8u << 20));                  // 16 KB
    unsigned* cellstart = (unsigned*)(ob + (8u << 20) + 65536);          // 16 KB
    unsigned* cursor    = (unsigned*)(ob + (8u << 20) + 131072);         // 16 KB
    uint4*    desc      = (uint4*)(ob + (9u << 20));                     // 68 KB

    hipMemsetAsync(vol, 0, VOLBYTES, stream);
    hipMemsetAsync(cellcnt, 0, CELLS * sizeof(unsigned), stream);
    taps_kernel<<<1, 256, 0, stream>>>(sigma, h);

    int nb = (n + HB * PPT - 1) / (HB * PPT);   // 489 blocks
    hist_kernel<<<nb, HB, 0, stream>>>(means, cellcnt, n);
    scan_kernel<<<1, 1024, 0, stream>>>(cellcnt, cellstart, cursor, desc);
    scatter_kernel<<<nb, HB, 0, stream>>>(means, weights, cursor, sorted, n);
    cellsplat_kernel<<<MAXCHUNKS, 256, 0, stream>>>(sorted, desc, vol);

    conv_d0_kernel<<<dim3(256, 4, 4), 256, 0, stream>>>(vol, out, h);   // blur dim0
    conv_d1_kernel<<<dim3(256, 4, 4), 256, 0, stream>>>(out, vol, h);   // blur dim1
    conv_d2_kernel<<<16384, 256, 0, stream>>>(vol, out, h);             // blur dim2
}

// Round 13
// 239.730 us; speedup vs baseline: 5.9210x; 1.0214x over previous
//
#include <hip/hip_runtime.h>
#include <math.h>

#define GN 256
#define VOLN (GN * GN * GN)
#define VOLBYTES ((size_t)VOLN * sizeof(float))
#define RAD 16          // truncation radius of the exact circular-conv kernel

// spatial cells: 16^3 voxels per cell, 16^3 = 4096 cells
#define CELLW 16
#define CPA   16
#define CELLS (CPA * CPA * CPA)
#define TILEW (CELLW + 1)                 // 17
#define TILEN (TILEW * TILEW * TILEW)     // 4913

#define HB  512         // threads per hist/scatter block
#define PPT 2           // points per thread
#define CHUNK 2048      // max points per cellsplat block
#define MAXCHUNKS 4352  // >= 4096 (1/cell) + 500000/2048 (+slack)
#define SB  1024        // threads per cellsplat block (16 waves: latency hiding)

#define CCH 32          // float4 per conv col-chunk (128 floats)

__device__ __forceinline__ int cell_of(float g0, float g1, float g2) {
    int b0 = (int)floorf(g0), b1 = (int)floorf(g1), b2 = (int)floorf(g2);
    b0 = min(max(b0, 0), 255); b1 = min(max(b1, 0), 255); b2 = min(max(b2, 0), 255);
    return ((b0 >> 4) << 8) | ((b1 >> 4) << 4) | (b2 >> 4);
}

// ---------------------------------------------------------------------------
// Pass 1: per-block LDS histogram.
// ---------------------------------------------------------------------------
__global__ __launch_bounds__(HB) void hist_kernel(const float* __restrict__ means,
                                                  unsigned* __restrict__ cellcnt, int n) {
    __shared__ unsigned lh[CELLS];
    int t = threadIdx.x;
    for (int i = t; i < CELLS; i += HB) lh[i] = 0u;
    __syncthreads();
    int base = blockIdx.x * (HB * PPT);
    for (int j = 0; j < PPT; ++j) {
        int p = base + j * HB + t;
        if (p < n) {
            float g0 = fmaf(means[3 * p + 0], 128.f, 128.f);
            float g1 = fmaf(means[3 * p + 1], 128.f, 128.f);
            float g2 = fmaf(means[3 * p + 2], 128.f, 128.f);
            atomicAdd(&lh[cell_of(g0, g1, g2)], 1u);
        }
    }
    __syncthreads();
    for (int i = t; i < CELLS; i += HB) {
        unsigned v = lh[i];
        if (v) atomicAdd(&cellcnt[i], v);
    }
}

// ---------------------------------------------------------------------------
// Pass 2: scan of cell counts -> cellstart/cursor; second scan over chunk
// counts -> chunk descriptors {cell, start, end}; sentinel-fill the rest.
// ---------------------------------------------------------------------------
__global__ __launch_bounds__(1024) void scan_kernel(const unsigned* __restrict__ cellcnt,
                                                    unsigned* __restrict__ cellstart,
                                                    unsigned* __restrict__ cursor,
                                                    uint4* __restrict__ desc) {
    __shared__ unsigned sums[1024];
    int t = threadIdx.x;
    unsigned c[4], loc[4], tot = 0u;
#pragma unroll
    for (int i = 0; i < 4; ++i) { c[i] = cellcnt[t * 4 + i]; loc[i] = tot; tot += c[i]; }
    sums[t] = tot;
    __syncthreads();
    for (int ofs = 1; ofs < 1024; ofs <<= 1) {
        unsigned v = (t >= ofs) ? sums[t - ofs] : 0u;
        __syncthreads();
        sums[t] += v;
        __syncthreads();
    }
    unsigned base = (t == 0) ? 0u : sums[t - 1];
    unsigned cs[4];
#pragma unroll
    for (int i = 0; i < 4; ++i) {
        cs[i] = base + loc[i];
        cellstart[t * 4 + i] = cs[i];
        cursor[t * 4 + i] = cs[i];
    }
    // ---- second scan: chunks per cell ----
    unsigned nch[4], lch[4], ctot = 0u;
#pragma unroll
    for (int i = 0; i < 4; ++i) { nch[i] = (c[i] + CHUNK - 1) / CHUNK; lch[i] = ctot; ctot += nch[i]; }
    __syncthreads();
    sums[t] = ctot;
    __syncthreads();
    for (int ofs = 1; ofs < 1024; ofs <<= 1) {
        unsigned v = (t >= ofs) ? sums[t - ofs] : 0u;
        __syncthreads();
        sums[t] += v;
        __syncthreads();
    }
    unsigned cbase = (t == 0) ? 0u : sums[t - 1];
#pragma unroll
    for (int i = 0; i < 4; ++i) {
        unsigned cb = cbase + lch[i];
        for (unsigned k = 0; k < nch[i]; ++k) {
            unsigned s0 = cs[i] + k * CHUNK;
            unsigned s1 = min(s0 + CHUNK, cs[i] + c[i]);
            desc[cb + k] = make_uint4((unsigned)(t * 4 + i), s0, s1, 0u);
        }
    }
    __syncthreads();
    unsigned total = sums[1023];
    for (unsigned i = total + t; i < MAXCHUNKS; i += 1024)
        desc[i] = make_uint4(0xFFFFFFFFu, 0u, 0u, 0u);
}

// ---------------------------------------------------------------------------
// Pass 3: 3-phase scatter (LDS count -> global reserve -> ranked placement).
// ---------------------------------------------------------------------------
__global__ __launch_bounds__(HB) void scatter_kernel(const float* __restrict__ means,
                                                     const float* __restrict__ weights,
                                                     unsigned* __restrict__ cursor,
                                                     float4* __restrict__ sorted, int n) {
    __shared__ unsigned lh[CELLS];
    int t = threadIdx.x;
    for (int i = t; i < CELLS; i += HB) lh[i] = 0u;
    __syncthreads();
    int base = blockIdx.x * (HB * PPT);
    for (int j = 0; j < PPT; ++j) {
        int p = base + j * HB + t;
        if (p < n) {
            float g0 = fmaf(means[3 * p + 0], 128.f, 128.f);
            float g1 = fmaf(means[3 * p + 1], 128.f, 128.f);
            float g2 = fmaf(means[3 * p + 2], 128.f, 128.f);
            atomicAdd(&lh[cell_of(g0, g1, g2)], 1u);
        }
    }
    __syncthreads();
    for (int i = t; i < CELLS; i += HB) {
        unsigned v = lh[i];
        lh[i] = v ? atomicAdd(&cursor[i], v) : 0u;   // lh now holds block's base
    }
    __syncthreads();
    for (int j = 0; j < PPT; ++j) {
        int p = base + j * HB + t;
        if (p < n) {
            float g0 = fmaf(means[3 * p + 0], 128.f, 128.f);
            float g1 = fmaf(means[3 * p + 1], 128.f, 128.f);
            float g2 = fmaf(means[3 * p + 2], 128.f, 128.f);
            unsigned pos = atomicAdd(&lh[cell_of(g0, g1, g2)], 1u);
            sorted[pos] = make_float4(g0, g1, g2, fmaxf(weights[p], 0.f));
        }
    }
}

// ---------------------------------------------------------------------------
// Pass 4: one 1024-thread block per CHUNK (16 waves -> latency hiding on the
// ~370 active blocks). Splat into 17^3 LDS tile, flush non-zeros by atomic.
// ---------------------------------------------------------------------------
__global__ __launch_bounds__(SB) void cellsplat_kernel(const float4* __restrict__ sorted,
                                                       const uint4* __restrict__ desc,
                                                       float* __restrict__ vol) {
    __shared__ float tile[TILEN];
    uint4 d = desc[blockIdx.x];
    if (d.x == 0xFFFFFFFFu) return;            // sentinel: unused block
    int c = (int)d.x;
    unsigned start = d.y, end = d.z;
    for (int i = threadIdx.x; i < TILEN; i += SB) tile[i] = 0.f;
    __syncthreads();
    int cb0 = (c >> 8) << 4, cb1 = ((c >> 4) & 15) << 4, cb2 = (c & 15) << 4;
    for (unsigned p0 = start; p0 < end; p0 += SB) {
        unsigned p = p0 + threadIdx.x;
        if (p < end) {
            float4 q = sorted[p];
            float f0 = floorf(q.x), f1 = floorf(q.y), f2 = floorf(q.z);
            int b0 = (int)f0, b1 = (int)f1, b2 = (int)f2;
            float r0 = q.x - f0, r1 = q.y - f1, r2 = q.z - f2;
            float c0v[2] = {1.f - r0, r0}, c1v[2] = {1.f - r1, r1}, c2v[2] = {1.f - r2, r2};
#pragma unroll
            for (int o0 = 0; o0 < 2; ++o0) {
                int v0 = b0 + o0, t0 = v0 - cb0;
                if ((unsigned)t0 > 16u || (unsigned)v0 > 255u) continue;
#pragma unroll
                for (int o1 = 0; o1 < 2; ++o1) {
                    int v1 = b1 + o1, t1 = v1 - cb1;
                    if ((unsigned)t1 > 16u || (unsigned)v1 > 255u) continue;
                    float w01 = c0v[o0] * c1v[o1] * q.w;
#pragma unroll
                    for (int o2 = 0; o2 < 2; ++o2) {
                        int v2 = b2 + o2, t2 = v2 - cb2;
                        if ((unsigned)t2 > 16u || (unsigned)v2 > 255u) continue;
                        atomicAdd(&tile[t0 * (TILEW * TILEW) + t1 * TILEW + t2], w01 * c2v[o2]);
                    }
                }
            }
        }
    }
    __syncthreads();
    for (int i = threadIdx.x; i < TILEN; i += SB) {
        float val = tile[i];
        if (val == 0.f) continue;
        int t0 = i / (TILEW * TILEW);
        int rem = i - t0 * (TILEW * TILEW);
        int t1 = rem / TILEW, t2 = rem - t1 * TILEW;
        int v0 = cb0 + t0, v1 = cb1 + t1, v2 = cb2 + t2;
        if (v0 < 256 && v1 < 256 && v2 < 256)
            atomicAdd(&vol[(v0 << 16) | (v1 << 8) | v2], val);
    }
}

// ---------------------------------------------------------------------------
// Exact 1-D blur taps (parallel DFT sum).
// ---------------------------------------------------------------------------
__global__ __launch_bounds__(256) void taps_kernel(const float* __restrict__ sigma_param,
                                                   float* __restrict__ h) {
    __shared__ float red[4];
    int k = threadIdx.x;
    float s = fmaxf(sigma_param[0], 0.f);
    int kk = (k < 128) ? k : k - 256;
    float f = (float)kk / 256.f;
    float cc = 2.f * (float)(M_PI * M_PI) * s * s;
    float term = expf(-cc * f * f);
    int wid = k >> 6, lane = k & 63;
    for (int m = 0; m <= RAD; ++m) {
        int idx = (k * m) & 255;
        float v = term * cosf((float)idx * (2.f * (float)M_PI / 256.f));
#pragma unroll
        for (int o = 32; o > 0; o >>= 1) v += __shfl_down(v, o, 64);
        if (lane == 0) red[wid] = v;
        __syncthreads();
        if (k == 0) h[m] = (red[0] + red[1] + red[2] + red[3]) * (1.f / 256.f);
        __syncthreads();
    }
}

// ---------------------------------------------------------------------------
// Separable circular convolutions — input-driven sliding window: each thread
// owns 8 consecutive output rows; each of 40 input rows is read ONCE from LDS
// and scattered into the accumulators it feeds (compile-time tap indices).
// float4 volume index: (i0<<14)|(i1<<6)|col4.
// ---------------------------------------------------------------------------
__global__ __launch_bounds__(256) void conv_d0_kernel(const float* __restrict__ in,
                                                      float* __restrict__ out,
                                                      const float* __restrict__ hh) {
    __shared__ float4 tile4[96][CCH];          // 48 KB
    float shv[17];
#pragma unroll
    for (int j = 0; j < 17; ++j) shv[j] = hh[j];
    float taps[33];
#pragma unroll
    for (int m = 0; m < 33; ++m) taps[m] = shv[m < 16 ? 16 - m : m - 16];
    int i1 = blockIdx.x, t0 = blockIdx.y, ch = blockIdx.z;
    int colbase4 = ch * CCH;
    const float4* in4 = (const float4*)in;
#pragma unroll
    for (int it = 0; it < (96 * CCH) / 256; ++it) {   // 12 iters
        int e = it * 256 + threadIdx.x;
        int r = e >> 5, cc = e & 31;
        int i0 = ((t0 << 6) + r - 16) & 255;
        tile4[r][cc] = in4[(i0 << 14) | (i1 << 6) | (colbase4 + cc)];
    }
    __syncthreads();
    int cg = threadIdx.x & 31;
    int b = (threadIdx.x >> 5) << 3;           // output row base 0,8,..,56
    float4 acc[8];
#pragma unroll
    for (int j = 0; j < 8; ++j) acc[j] = make_float4(0.f, 0.f, 0.f, 0.f);
#pragma unroll
    for (int k = 0; k < 40; ++k) {             // input rows b..b+39 (read once)
        float4 v = tile4[b + k][cg];
#pragma unroll
        for (int j = 0; j < 8; ++j) {
            if (k - j >= 0 && k - j <= 32) {   // tap m = k - j, compile-time
                float tp = taps[k - j];
                acc[j].x = fmaf(tp, v.x, acc[j].x);
                acc[j].y = fmaf(tp, v.y, acc[j].y);
                acc[j].z = fmaf(tp, v.z, acc[j].z);
                acc[j].w = fmaf(tp, v.w, acc[j].w);
            }
        }
    }
#pragma unroll
    for (int j = 0; j < 8; ++j) {
        int o0 = (t0 << 6) + b + j;
        ((float4*)out)[(o0 << 14) | (i1 << 6) | (colbase4 + cg)] = acc[j];
    }
}

__global__ __launch_bounds__(256) void conv_d1_kernel(const float* __restrict__ in,
                                                      float* __restrict__ out,
                                                      const float* __restrict__ hh) {
    __shared__ float4 tile4[96][CCH];
    float shv[17];
#pragma unroll
    for (int j = 0; j < 17; ++j) shv[j] = hh[j];
    float taps[33];
#pragma unroll
    for (int m = 0; m < 33; ++m) taps[m] = shv[m < 16 ? 16 - m : m - 16];
    int i0 = blockIdx.x, t1 = blockIdx.y, ch = blockIdx.z;
    int colbase4 = ch * CCH;
    const float4* in4 = (const float4*)in;
#pragma unroll
    for (int it = 0; it < (96 * CCH) / 256; ++it) {
        int e = it * 256 + threadIdx.x;
        int r = e >> 5, cc = e & 31;
        int i1 = ((t1 << 6) + r - 16) & 255;
        tile4[r][cc] = in4[(i0 << 14) | (i1 << 6) | (colbase4 + cc)];
    }
    __syncthreads();
    int cg = threadIdx.x & 31;
    int b = (threadIdx.x >> 5) << 3;
    float4 acc[8];
#pragma unroll
    for (int j = 0; j < 8; ++j) acc[j] = make_float4(0.f, 0.f, 0.f, 0.f);
#pragma unroll
    for (int k = 0; k < 40; ++k) {
        float4 v = tile4[b + k][cg];
#pragma unroll
        for (int j = 0; j < 8; ++j) {
            if (k - j >= 0 && k - j <= 32) {
                float tp = taps[k - j];
                acc[j].x = fmaf(tp, v.x, acc[j].x);
                acc[j].y = fmaf(tp, v.y, acc[j].y);
                acc[j].z = fmaf(tp, v.z, acc[j].z);
                acc[j].w = fmaf(tp, v.w, acc[j].w);
            }
        }
    }
#pragma unroll
    for (int j = 0; j < 8; ++j) {
        int o1 = (t1 << 6) + b + j;
        ((float4*)out)[(i0 << 14) | (o1 << 6) | (colbase4 + cg)] = acc[j];
    }
}

// conv along i2 (contiguous): unchanged (not the bottleneck).
__global__ __launch_bounds__(256) void conv_d2_kernel(const float* __restrict__ in,
                                                      float* __restrict__ out,
                                                      const float* __restrict__ hh) {
    __shared__ float tile[4][256];
    float shv[17];
#pragma unroll
    for (int j = 0; j < 17; ++j) shv[j] = hh[j];
    int bx = blockIdx.x;                       // 16384 blocks
    size_t base = (size_t)bx * 1024;
#pragma unroll
    for (int it = 0; it < 4; ++it) {
        int e = it * 256 + threadIdx.x;
        ((float*)tile)[e] = in[base + e];
    }
    __syncthreads();
    int ri = threadIdx.x >> 6;                 // row 0..3
    int k = threadIdx.x & 63;                  // float4 chunk index
    const float4* row4 = (const float4*)tile[ri];
    float w[36];
#pragma unroll
    for (int j = 0; j < 9; ++j) {
        float4 q = row4[(k - 4 + j) & 63];
        w[4 * j + 0] = q.x; w[4 * j + 1] = q.y; w[4 * j + 2] = q.z; w[4 * j + 3] = q.w;
    }
    float acc[4] = {0.f, 0.f, 0.f, 0.f};
#pragma unroll
    for (int kk = 0; kk < 36; ++kk) {
#pragma unroll
        for (int i = 0; i < 4; ++i) {
            int d = kk - 16 - i;
            if (d >= -16 && d <= 16) acc[i] = fmaf(shv[d < 0 ? -d : d], w[kk], acc[i]);
        }
    }
    ((float4*)out)[(size_t)bx * 256 + ri * 64 + k] = make_float4(acc[0], acc[1], acc[2], acc[3]);
}

// ---------------------------------------------------------------------------
extern "C" void kernel_launch(void* const* d_in, const int* in_sizes, int n_in,
                              void* d_out, int out_size, void* d_ws, size_t ws_size,
                              hipStream_t stream) {
    const float* means   = (const float*)d_in[0];
    const float* weights = (const float*)d_in[1];
    const float* sigma   = (const float*)d_in[2];
    int n = in_sizes[1];                        // 500000 points

    float* vol = (float*)d_ws;                  // 64 MB scratch volume
    float* h   = (float*)((char*)d_ws + VOLBYTES);
    float* out = (float*)d_out;

    // scratch metadata in d_out (all dead before conv_d0 overwrites d_out)
    char* ob = (char*)d_out;
    float4*   sorted    = (float4*)ob;                                   // 8 MB
    unsigned* cellcnt   = (unsigned*)(ob + (8u << 20));                  // 16 KB
    unsigned* cellstart = (unsigned*)(ob + (8u << 20) + 65536);          // 16 KB
    unsigned* cursor    = (unsigned*)(ob + (8u << 20) + 131072);         // 16 KB
    uint4*    desc      = (uint4*)(ob + (9u << 20));                     // 68 KB

    hipMemsetAsync(vol, 0, VOLBYTES, stream);
    hipMemsetAsync(cellcnt, 0, CELLS * sizeof(unsigned), stream);
    taps_kernel<<<1, 256, 0, stream>>>(sigma, h);

    int nb = (n + HB * PPT - 1) / (HB * PPT);   // 489 blocks
    hist_kernel<<<nb, HB, 0, stream>>>(means, cellcnt, n);
    scan_kernel<<<1, 1024, 0, stream>>>(cellcnt, cellstart, cursor, desc);
    scatter_kernel<<<nb, HB, 0, stream>>>(means, weights, cursor, sorted, n);
    cellsplat_kernel<<<MAXCHUNKS, SB, 0, stream>>>(sorted, desc, vol);

    conv_d0_kernel<<<dim3(256, 4, 2), 256, 0, stream>>>(vol, out, h);   // blur dim0
    conv_d1_kernel<<<dim3(256, 4, 2), 256, 0, stream>>>(out, vol, h);   // blur dim1
    conv_d2_kernel<<<16384, 256, 0, stream>>>(vol, out, h);             // blur dim2
}